// Round 16
// baseline (158.865 us; speedup 1.0000x reference)
//
#include <hip/hip_runtime.h>
#include <cfloat>

// Problem constants: M=N=64 grid, DIM=512, B=4096, SIGMA=32
#define DIMK 512
#define MN   4096
#define BATCH 4096
#define BK 32
#define NGRP 1024   // 4-column groups per row

typedef _Float16 half8_t __attribute__((ext_vector_type(8)));
typedef float f32x4 __attribute__((ext_vector_type(4)));

// async global->LDS, 16B per lane; LDS dest is wave-uniform base + lane*16
#define GLD16(gp, lp) __builtin_amdgcn_global_load_lds( \
    (const __attribute__((address_space(1))) void*)(gp), \
    (__attribute__((address_space(3))) void*)(lp), 16, 0, 0)

// ---------------------------------------------------------------------------
// Convert: X,W fp32 -> f16 RTN + exact fp32 row norms. (unchanged from R15)
// ---------------------------------------------------------------------------
__global__ __launch_bounds__(256) void convert_kernel(
        const float* __restrict__ X, const float* __restrict__ W,
        _Float16* __restrict__ Xh, _Float16* __restrict__ Wh,
        float* __restrict__ w2, float* __restrict__ xnorm) {
    const int blk  = blockIdx.x;
    const int t    = threadIdx.x;
    const bool isW = blk >= 1024;
    const float* src = isW ? W : X;
    _Float16* dst  = isW ? Wh : Xh;
    const int rblk = isW ? blk - 1024 : blk;
    const size_t idx = (size_t)rblk * 2048 + (size_t)t * 8;

    float4 v0 = *(const float4*)(src + idx);
    float4 v1 = *(const float4*)(src + idx + 4);
    float v[8] = {v0.x, v0.y, v0.z, v0.w, v1.x, v1.y, v1.z, v1.w};
    half8_t hv;
    float s = 0.f;
#pragma unroll
    for (int e = 0; e < 8; e++) {
        s += v[e] * v[e];
        hv[e] = (_Float16)v[e];
    }
    *(half8_t*)(dst + idx) = hv;
#pragma unroll
    for (int o = 32; o > 0; o >>= 1) s += __shfl_down(s, o);
    if ((t & 63) == 0) {
        int row = rblk * 4 + (t >> 6);
        if (isW) w2[row] = s;
        else     xnorm[row] = __fsqrt_rn(s);
    }
}

// ---------------------------------------------------------------------------
// Approx score GEMM, group-min output (R15 semantics). NEW structure:
// only B is staged through LDS (8KB/buf dbuf, 1 barrier/iter guards 2 GLD16s
// per wave); A fragments load global->VGPR directly (A-frag layout == clean
// 16B/lane load, verified R6), register double-buffered — A latency is
// per-wave (vmcnt), outside the barrier lockstep. 4 blocks/CU.
// Group-mins land in the first 4KB of row b's own d_out region (same
// self-aliasing bijection as R14/R15).
// ---------------------------------------------------------------------------
__global__ __launch_bounds__(256, 4) void score_kernel(
        const _Float16* __restrict__ Xh, const _Float16* __restrict__ Wh,
        const float* __restrict__ w2, float* __restrict__ Gm /* = d_out */) {
    __shared__ __align__(16) _Float16 lds[2][4096];  // B tile only, 8KB/buf

    const int t    = threadIdx.x;
    const int lane = t & 63;
    const int w    = t >> 6;        // wave 0..3
    const int wm   = w >> 1;        // wave m-half
    const int wn   = w & 1;         // wave n-half
    const int m0   = blockIdx.y * 128;
    const int n0   = blockIdx.x * 128;

    f32x4 acc[4][4];
#pragma unroll
    for (int i = 0; i < 4; i++)
#pragma unroll
        for (int j = 0; j < 4; j++) acc[i][j] = (f32x4){0.f, 0.f, 0.f, 0.f};

    const int r16 = lane & 15;
    const int kg  = lane >> 4;
    const size_t ko = (size_t)kg * 8;

    // B staging: wave w deposits 16-row groups (2w, 2w+1), 1KB each.
    const int b0 = 2 * w, b1 = 2 * w + 1;
    const _Float16* gB0 = Wh + (size_t)(n0 + b0 * 16 + r16) * DIMK + ko;
    const _Float16* gB1 = Wh + (size_t)(n0 + b1 * 16 + r16) * DIMK + ko;
    const int dB0 = b0 * 512, dB1 = b1 * 512;

    // A fragments: wave-private direct loads, rows m0 + wm*64 + i*16 + r16.
    const _Float16* gA[4];
#pragma unroll
    for (int i = 0; i < 4; i++)
        gA[i] = Xh + (size_t)(m0 + wm * 64 + i * 16 + r16) * DIMK + ko;

    // prologue: B(0) -> buf0; A(0) -> regs
    GLD16(gB0, &lds[0][dB0]);
    GLD16(gB1, &lds[0][dB1]);
    half8_t ac[4];
#pragma unroll
    for (int i = 0; i < 4; i++) ac[i] = *(const half8_t*)(gA[i]);

    int cur = 0;
    for (int k0 = 0; k0 < DIMK; k0 += BK) {
        __syncthreads();               // B(cur) staged; prior B reads done
        const bool more = (k0 + BK) < DIMK;
        const int  nk   = more ? (k0 + BK) : 0;
        if (more) {                    // B(k+1) -> alternate buf (async)
            GLD16(gB0 + nk, &lds[cur ^ 1][dB0]);
            GLD16(gB1 + nk, &lds[cur ^ 1][dB1]);
        }
        // A(k+1) -> next regs (plain loads, complete during MFMA phase)
        half8_t an[4];
#pragma unroll
        for (int i = 0; i < 4; i++) an[i] = *(const half8_t*)(gA[i] + nk);
        // B(k) fragments from LDS
        const _Float16* sB = &lds[cur][0];
        half8_t bh[4];
#pragma unroll
        for (int j = 0; j < 4; j++)
            bh[j] = *(const half8_t*)(sB + (wn * 4 + j) * 512 + lane * 8);
        // 16 MFMA
#pragma unroll
        for (int i = 0; i < 4; i++)
#pragma unroll
            for (int j = 0; j < 4; j++)
                acc[i][j] = __builtin_amdgcn_mfma_f32_16x16x32_f16(ac[i], bh[j], acc[i][j], 0, 0, 0);
#pragma unroll
        for (int i = 0; i < 4; i++) ac[i] = an[i];
        cur ^= 1;
    }

    // ---- 4-col group mins. D layout: col = lane&15, row = (lane>>4)*4+v ----
    const int q   = lane >> 4;
    const int cl  = lane & 15;
    const int gb  = (n0 >> 2) + wn * 16;      // group base for this wave
    float w2v[4];
#pragma unroll
    for (int j = 0; j < 4; j++) w2v[j] = w2[n0 + wn * 64 + j * 16 + cl];
#pragma unroll
    for (int i = 0; i < 4; i++)
#pragma unroll
        for (int v = 0; v < 4; v++) {
            const int row = m0 + wm * 64 + i * 16 + q * 4 + v;
            float* grow = Gm + (size_t)row * 4096 + gb;
#pragma unroll
            for (int j = 0; j < 4; j++) {
                float s = w2v[j] - 2.0f * acc[i][j][v];
                s = fminf(s, __shfl_xor(s, 1));
                s = fminf(s, __shfl_xor(s, 2));
                if ((cl & 3) == 0) grow[j * 4 + (cl >> 2)] = s;
            }
        }
}

// ---------------------------------------------------------------------------
// Epilogue (unchanged from R15): per-row group-min screen + exact fp32
// rescore of qualifying columns + separable Gaussian row write.
// ---------------------------------------------------------------------------
__global__ __launch_bounds__(256) void epilogue_kernel(
        const float* __restrict__ w2, const float* __restrict__ xnorm,
        const float* __restrict__ X, const float* __restrict__ W,
        const int* __restrict__ decay_p, const int* __restrict__ it_p,
        float* out) {
    __shared__ float xs[512];
    __shared__ int   list[NGRP];
    __shared__ int   cnt;
    __shared__ float wmin[4];
    __shared__ float svv[4];
    __shared__ int   svi[4];
    __shared__ float sbv;
    __shared__ int   sbi;
    __shared__ float tab[128];
    const int row  = blockIdx.x;
    const int t    = threadIdx.x;
    const int lane = t & 63;
    const int w    = t >> 6;

    {
        float2 xv = *(const float2*)(X + (size_t)row * DIMK + t * 2);
        xs[2 * t]     = xv.x;
        xs[2 * t + 1] = xv.y;
    }
    if (t == 0) { cnt = 0; sbv = FLT_MAX; sbi = 0x7FFFFFFF; }

    f32x4 gm = *((const f32x4*)(out + (size_t)row * 4096) + t);
    float g = fminf(fminf(gm[0], gm[1]), fminf(gm[2], gm[3]));
#pragma unroll
    for (int mask = 1; mask <= 32; mask <<= 1)
        g = fminf(g, __shfl_xor(g, mask));
    if (lane == 0) wmin[w] = g;
    __syncthreads();
    const float gmin = fminf(fminf(wmin[0], wmin[1]), fminf(wmin[2], wmin[3]));
    const float tau  = gmin + 2.0f * (0.0222f * xnorm[row] + 0.1f);

#pragma unroll
    for (int e = 0; e < 4; e++)
        if (gm[e] <= tau) list[atomicAdd(&cnt, 1)] = t * 4 + e;
    __syncthreads();
    const int total = cnt;            // >= 1 always

    for (int idx = 0; idx < total; idx++) {
        const int col = list[idx] * 4 + w;
        const float* wr = W + (size_t)col * DIMK;
        float p = 0.f;
#pragma unroll
        for (int e = 0; e < 8; e++) p += xs[lane * 8 + e] * wr[lane * 8 + e];
#pragma unroll
        for (int mask = 1; mask <= 32; mask <<= 1) p += __shfl_xor(p, mask);
        if (lane == 0) {
            svv[w] = w2[col] - 2.0f * p;
            svi[w] = col;
        }
        __syncthreads();
        if (t == 0) {
#pragma unroll
            for (int k = 0; k < 4; k++) {
                float s = svv[k]; int c = svi[k];
                if (s < sbv || (s == sbv && c < sbi)) { sbv = s; sbi = c; }
            }
        }
        __syncthreads();
    }

    const float lr  = __expf(-(float)(*it_p) / (float)(*decay_p));
    const float so  = 32.0f * lr;          // SIGMA = 32
    const float inv = 1.0f / (so * so);
    const int rr = sbi >> 6, cc = sbi & 63;
    if (t < 64) {
        float d = (float)(t - rr);
        tab[t] = __expf(-d * d * inv);
    } else if (t < 128) {
        float d = (float)(t - 64 - cc);
        tab[t] = __expf(-d * d * inv);
    }
    __syncthreads();
    const float* er = tab;
    const float* ec = tab + 64;
    f32x4* orow = (f32x4*)(out + (size_t)row * 4096);
#pragma unroll
    for (int qq = 0; qq < 4; qq++) {
        int f  = qq * 256 + t;
        int i  = f >> 4;
        int j0 = (f & 15) * 4;
        float e = er[i];
        f32x4 o = {e * ec[j0], e * ec[j0 + 1], e * ec[j0 + 2], e * ec[j0 + 3]};
        __builtin_nontemporal_store(o, orow + f);
    }
}

// ---------------------------------------------------------------------------
extern "C" void kernel_launch(void* const* d_in, const int* in_sizes, int n_in,
                              void* d_out, int out_size, void* d_ws, size_t ws_size,
                              hipStream_t stream) {
    const float* X       = (const float*)d_in[0];   // [4096,512]
    const float* W       = (const float*)d_in[1];   // [4096,512]
    const int*   decay_p = (const int*)d_in[3];
    const int*   it_p    = (const int*)d_in[4];
    float* out = (float*)d_out;                     // doubles as group-min scratch

    // ws: Xh (4MB) | Wh (4MB) | w2 16KB | xnorm 16KB
    _Float16* Xh = (_Float16*)d_ws;
    _Float16* Wh = Xh + (size_t)BATCH * DIMK;
    float*    w2 = (float*)(Wh + (size_t)MN * DIMK);
    float*    xn = w2 + MN;

    convert_kernel<<<2048, 256, 0, stream>>>(X, W, Xh, Wh, w2, xn);
    score_kernel<<<dim3(32, 32), 256, 0, stream>>>(Xh, Wh, w2, out);
    epilogue_kernel<<<BATCH, 256, 0, stream>>>(w2, xn, X, W, decay_p, it_p, out);
}

// Round 17
// 144.229 us; speedup vs baseline: 1.1015x; 1.1015x over previous
//
#include <hip/hip_runtime.h>
#include <cfloat>

// Problem constants: M=N=64 grid, DIM=512, B=4096, SIGMA=32
#define DIMK 512
#define MN   4096
#define BATCH 4096
#define BK 32
#define NGRP 1024   // 4-column groups per row

typedef _Float16 half8_t __attribute__((ext_vector_type(8)));
typedef _Float16 half4_t __attribute__((ext_vector_type(4)));
typedef float f32x4 __attribute__((ext_vector_type(4)));

// async global->LDS, 16B per lane; LDS dest is wave-uniform base + lane*16
#define GLD16(gp, lp) __builtin_amdgcn_global_load_lds( \
    (const __attribute__((address_space(1))) void*)(gp), \
    (__attribute__((address_space(3))) void*)(lp), 16, 0, 0)

// ---------------------------------------------------------------------------
// Convert: X,W fp32 -> f16 RTN + exact fp32 row norms. (unchanged from R15)
// ---------------------------------------------------------------------------
__global__ __launch_bounds__(256) void convert_kernel(
        const float* __restrict__ X, const float* __restrict__ W,
        _Float16* __restrict__ Xh, _Float16* __restrict__ Wh,
        float* __restrict__ w2, float* __restrict__ xnorm) {
    const int blk  = blockIdx.x;
    const int t    = threadIdx.x;
    const bool isW = blk >= 1024;
    const float* src = isW ? W : X;
    _Float16* dst  = isW ? Wh : Xh;
    const int rblk = isW ? blk - 1024 : blk;
    const size_t idx = (size_t)rblk * 2048 + (size_t)t * 8;

    float4 v0 = *(const float4*)(src + idx);
    float4 v1 = *(const float4*)(src + idx + 4);
    float v[8] = {v0.x, v0.y, v0.z, v0.w, v1.x, v1.y, v1.z, v1.w};
    half8_t hv;
    float s = 0.f;
#pragma unroll
    for (int e = 0; e < 8; e++) {
        s += v[e] * v[e];
        hv[e] = (_Float16)v[e];
    }
    *(half8_t*)(dst + idx) = hv;
#pragma unroll
    for (int o = 32; o > 0; o >>= 1) s += __shfl_down(s, o);
    if ((t & 63) == 0) {
        int row = rblk * 4 + (t >> 6);
        if (isW) w2[row] = s;
        else     xnorm[row] = __fsqrt_rn(s);
    }
}

// ---------------------------------------------------------------------------
// Approx score GEMM (R15 structure — best measured): A+B staged via LDS
// dbuf 2x16KB, BK=32, 1 barrier/iter, 4 blocks/CU. Group-mins now stored
// as F16 (payload halved) into the first 2KB of row b's own d_out region
// (same self-aliasing bijection: epilogue block b reads only its own row's
// bytes before overwriting them).
// ---------------------------------------------------------------------------
__global__ __launch_bounds__(256, 4) void score_kernel(
        const _Float16* __restrict__ Xh, const _Float16* __restrict__ Wh,
        const float* __restrict__ w2, float* __restrict__ Gm /* = d_out */) {
    __shared__ __align__(16) _Float16 lds[2][8192];  // Ah[4096] | Bh[4096]

    const int t    = threadIdx.x;
    const int lane = t & 63;
    const int w    = t >> 6;        // wave 0..3
    const int wm   = w >> 1;        // wave m-half
    const int wn   = w & 1;         // wave n-half
    const int m0   = blockIdx.y * 128;
    const int n0   = blockIdx.x * 128;

    f32x4 acc[4][4];
#pragma unroll
    for (int i = 0; i < 4; i++)
#pragma unroll
        for (int j = 0; j < 4; j++) acc[i][j] = (f32x4){0.f, 0.f, 0.f, 0.f};

    const int r16 = lane & 15;
    const int kg  = lane >> 4;
    const int b0  = 2 * w, b1 = 2 * w + 1;
    const size_t ko = (size_t)kg * 8;
    const _Float16* gA0 = Xh + (size_t)(m0 + b0 * 16 + r16) * DIMK + ko;
    const _Float16* gA1 = Xh + (size_t)(m0 + b1 * 16 + r16) * DIMK + ko;
    const _Float16* gB0 = Wh + (size_t)(n0 + b0 * 16 + r16) * DIMK + ko;
    const _Float16* gB1 = Wh + (size_t)(n0 + b1 * 16 + r16) * DIMK + ko;
    const int dA0 = b0 * 512,        dA1 = b1 * 512;
    const int dB0 = 4096 + b0 * 512, dB1 = 4096 + b1 * 512;

    GLD16(gA0, &lds[0][dA0]);
    GLD16(gA1, &lds[0][dA1]);
    GLD16(gB0, &lds[0][dB0]);
    GLD16(gB1, &lds[0][dB1]);

    int cur = 0;
    for (int k0 = 0; k0 < DIMK; k0 += BK) {
        __syncthreads();
        if (k0 + BK < DIMK) {
            int nk = k0 + BK;
            GLD16(gA0 + nk, &lds[cur ^ 1][dA0]);
            GLD16(gA1 + nk, &lds[cur ^ 1][dA1]);
            GLD16(gB0 + nk, &lds[cur ^ 1][dB0]);
            GLD16(gB1 + nk, &lds[cur ^ 1][dB1]);
        }
        const _Float16* sA = &lds[cur][0];
        const _Float16* sB = &lds[cur][4096];

        half8_t ah[4], bh[4];
#pragma unroll
        for (int i = 0; i < 4; i++) {
            ah[i] = *(const half8_t*)(sA + (wm * 4 + i) * 512 + lane * 8);
            bh[i] = *(const half8_t*)(sB + (wn * 4 + i) * 512 + lane * 8);
        }
#pragma unroll
        for (int i = 0; i < 4; i++)
#pragma unroll
            for (int j = 0; j < 4; j++)
                acc[i][j] = __builtin_amdgcn_mfma_f32_16x16x32_f16(ah[i], bh[j], acc[i][j], 0, 0, 0);
        cur ^= 1;
    }

    // ---- 4-col group mins -> f16. D layout: col=lane&15, row=(lane>>4)*4+v ----
    const int q   = lane >> 4;
    const int cl  = lane & 15;
    const int gb  = (n0 >> 2) + wn * 16;      // group base for this wave
    float w2v[4];
#pragma unroll
    for (int j = 0; j < 4; j++) w2v[j] = w2[n0 + wn * 64 + j * 16 + cl];
#pragma unroll
    for (int i = 0; i < 4; i++)
#pragma unroll
        for (int v = 0; v < 4; v++) {
            const int row = m0 + wm * 64 + i * 16 + q * 4 + v;
            _Float16* grow = (_Float16*)Gm + (size_t)row * 8192 + gb;
#pragma unroll
            for (int j = 0; j < 4; j++) {
                float s = w2v[j] - 2.0f * acc[i][j][v];
                s = fminf(s, __shfl_xor(s, 1));
                s = fminf(s, __shfl_xor(s, 2));
                if ((cl & 3) == 0) grow[j * 4 + (cl >> 2)] = (_Float16)s;
            }
        }
}

// ---------------------------------------------------------------------------
// Epilogue: per-row f16 group-min screen + BARRIER-FREE exact fp32 rescore
// (waves own candidate groups independently; single merge sync) + separable
// Gaussian row write (nontemporal). Margin: tau = gmin + 2*(2^-10*||x||*
// sqrt(512) + 0.25) — extra 0.15 absolute covers f16 storage rounding of the
// group-min values (|s| <= ~150 -> <= 0.07 each side).
// ---------------------------------------------------------------------------
__global__ __launch_bounds__(256) void epilogue_kernel(
        const float* __restrict__ w2, const float* __restrict__ xnorm,
        const float* __restrict__ X, const float* __restrict__ W,
        const int* __restrict__ decay_p, const int* __restrict__ it_p,
        float* out) {
    __shared__ float xs[512];
    __shared__ int   list[NGRP];
    __shared__ int   cnt;
    __shared__ float wmin[4];
    __shared__ float svv[4];
    __shared__ int   svi[4];
    __shared__ float tab[128];
    const int row  = blockIdx.x;
    const int t    = threadIdx.x;
    const int lane = t & 63;
    const int w    = t >> 6;

    {
        float2 xv = *(const float2*)(X + (size_t)row * DIMK + t * 2);
        xs[2 * t]     = xv.x;
        xs[2 * t + 1] = xv.y;
    }
    if (t == 0) cnt = 0;

    // f16 group-mins: 4 per thread (8B coalesced)
    half4_t gmh = *((const half4_t*)((const _Float16*)out + (size_t)row * 8192) + t);
    float gme[4] = {(float)gmh[0], (float)gmh[1], (float)gmh[2], (float)gmh[3]};
    float g = fminf(fminf(gme[0], gme[1]), fminf(gme[2], gme[3]));
#pragma unroll
    for (int mask = 1; mask <= 32; mask <<= 1)
        g = fminf(g, __shfl_xor(g, mask));
    if (lane == 0) wmin[w] = g;
    __syncthreads();
    const float gmin = fminf(fminf(wmin[0], wmin[1]), fminf(wmin[2], wmin[3]));
    const float tau  = gmin + 2.0f * (0.0222f * xnorm[row] + 0.25f);

    // collect qualifying groups (unordered; explicit col tie-break later)
#pragma unroll
    for (int e = 0; e < 4; e++)
        if (gme[e] <= tau) list[atomicAdd(&cnt, 1)] = t * 4 + e;
    __syncthreads();
    const int total = cnt;            // >= 1 always (gmin's group qualifies)

    // barrier-free exact rescore: wave w owns groups w, w+4, w+8, ...
    float mbv = FLT_MAX;
    int   mbi = 0x7FFFFFFF;
    for (int idx = w; idx < total; idx += 4) {
        const int gid = list[idx];
#pragma unroll
        for (int cj = 0; cj < 4; cj++) {
            const int col = gid * 4 + cj;
            const float* wr = W + (size_t)col * DIMK;
            float p = 0.f;
#pragma unroll
            for (int e = 0; e < 8; e++) p += xs[lane * 8 + e] * wr[lane * 8 + e];
#pragma unroll
            for (int mask = 1; mask <= 32; mask <<= 1) p += __shfl_xor(p, mask);
            float s = w2[col] - 2.0f * p;
            if (s < mbv || (s == mbv && col < mbi)) { mbv = s; mbi = col; }
        }
    }
    if (lane == 0) { svv[w] = mbv; svi[w] = mbi; }
    __syncthreads();
    // merge (uniform across all threads; no extra sync needed)
    float sbv = svv[0]; int sbi = svi[0];
#pragma unroll
    for (int k = 1; k < 4; k++) {
        float s = svv[k]; int c = svi[k];
        if (s < sbv || (s == sbv && c < sbi)) { sbv = s; sbi = c; }
    }

    // separable Gaussian tables + row write (overwrites group-mins)
    const float lr  = __expf(-(float)(*it_p) / (float)(*decay_p));
    const float so  = 32.0f * lr;          // SIGMA = 32
    const float inv = 1.0f / (so * so);
    const int rr = sbi >> 6, cc = sbi & 63;
    if (t < 64) {
        float d = (float)(t - rr);
        tab[t] = __expf(-d * d * inv);
    } else if (t < 128) {
        float d = (float)(t - 64 - cc);
        tab[t] = __expf(-d * d * inv);
    }
    __syncthreads();
    const float* er = tab;
    const float* ec = tab + 64;
    f32x4* orow = (f32x4*)(out + (size_t)row * 4096);
#pragma unroll
    for (int qq = 0; qq < 4; qq++) {
        int f  = qq * 256 + t;
        int i  = f >> 4;
        int j0 = (f & 15) * 4;
        float e = er[i];
        f32x4 o = {e * ec[j0], e * ec[j0 + 1], e * ec[j0 + 2], e * ec[j0 + 3]};
        __builtin_nontemporal_store(o, orow + f);
    }
}

// ---------------------------------------------------------------------------
extern "C" void kernel_launch(void* const* d_in, const int* in_sizes, int n_in,
                              void* d_out, int out_size, void* d_ws, size_t ws_size,
                              hipStream_t stream) {
    const float* X       = (const float*)d_in[0];   // [4096,512]
    const float* W       = (const float*)d_in[1];   // [4096,512]
    const int*   decay_p = (const int*)d_in[3];
    const int*   it_p    = (const int*)d_in[4];
    float* out = (float*)d_out;                     // doubles as group-min scratch

    // ws: Xh (4MB) | Wh (4MB) | w2 16KB | xnorm 16KB
    _Float16* Xh = (_Float16*)d_ws;
    _Float16* Wh = Xh + (size_t)BATCH * DIMK;
    float*    w2 = (float*)(Wh + (size_t)MN * DIMK);
    float*    xn = w2 + MN;

    convert_kernel<<<2048, 256, 0, stream>>>(X, W, Xh, Wh, w2, xn);
    score_kernel<<<dim3(32, 32), 256, 0, stream>>>(Xh, Wh, w2, out);
    epilogue_kernel<<<BATCH, 256, 0, stream>>>(w2, xn, X, W, decay_p, it_p, out);
}